// Round 6
// baseline (322.873 us; speedup 1.0000x reference)
//
#include <hip/hip_runtime.h>
#include <math.h>

#define NROWS 64
#define DCOLS 512
#define BDIM  512
#define NWAVES 8
#define RPW   8     // rows per wave: 64 rows / 8 waves

typedef float f32x4 __attribute__((ext_vector_type(4)));

__device__ __forceinline__ float hsum8(f32x4 a, f32x4 b) {
    return ((a.x + a.y) + (a.z + a.w)) + ((b.x + b.y) + (b.z + b.w));
}
__device__ __forceinline__ float hsumsq8(f32x4 a, f32x4 b) {
    return (a.x*a.x + a.y*a.y + a.z*a.z + a.w*a.w)
         + (b.x*b.x + b.y*b.y + b.z*b.z + b.w*b.w);
}

__device__ __forceinline__ void wave_reduce_sum2(float& a, float& b) {
#pragma unroll
    for (int off = 32; off > 0; off >>= 1) {
        a += __shfl_xor(a, off, 64);
        b += __shfl_xor(b, off, 64);
    }
}
__device__ __forceinline__ float wave_reduce_sum(float v) {
#pragma unroll
    for (int off = 32; off > 0; off >>= 1)
        v += __shfl_xor(v, off, 64);
    return v;
}
__device__ __forceinline__ float wave_reduce_max(float v) {
#pragma unroll
    for (int off = 32; off > 0; off >>= 1)
        v = fmaxf(v, __shfl_xor(v, off, 64));
    return v;
}

// tanh(x) = 1 - 2/(exp(2x)+1); correct both signs, saturates at +/-1.
__device__ __forceinline__ float fast_tanh(float x) {
    float e = __expf(2.0f * x);
    return 1.0f - 2.0f / (e + 1.0f);
}

__global__ __launch_bounds__(BDIM, 6) void fused_ln_attn_kernel(
    const float* __restrict__ emb,
    const float* __restrict__ gamma,
    const float* __restrict__ beta,
    const float* __restrict__ Wv,
    const float* __restrict__ bv,
    float* __restrict__ out)
{
    __shared__ float s_q[DCOLS];
    __shared__ float s_sc[NROWS];    // scores; s_sc[0] = -inf sentinel
    __shared__ float s_nmu[NROWS];   // -mu*rs per row
    __shared__ float s_rs[NROWS];    // rs per row

    const int tid  = threadIdx.x;
    const int wave = tid >> 6;
    const int lane = tid & 63;
    const int c0   = lane << 2;
    const int c1   = 256 + (lane << 2);

    const size_t base = (size_t)blockIdx.x * (size_t)(NROWS * DCOLS);
    const float* eb = emb + base;
    float*       ob = out + base;

    // per-column params (stay in regs whole kernel: 24 VGPR + q 8)
    const f32x4 g0 = *(const f32x4*)(gamma + c0);
    const f32x4 g1 = *(const f32x4*)(gamma + c1);
    const f32x4 b0 = *(const f32x4*)(beta + c0);
    const f32x4 b1 = *(const f32x4*)(beta + c1);
    const f32x4 w0 = *(const f32x4*)(Wv + c0);
    const f32x4 w1 = *(const f32x4*)(Wv + c1);
    const float bias = bv[0];

    const int r0 = wave * RPW;
    // prefetch own first row (for wave 0 this IS the query row)
    const f32x4 px0 = *(const f32x4*)(eb + r0 * DCOLS + c0);
    const f32x4 px1 = *(const f32x4*)(eb + r0 * DCOLS + c1);

    if (wave == 0) {
        float s = hsum8(px0, px1), ss = hsumsq8(px0, px1);
        wave_reduce_sum2(s, ss);
        const float mu  = s * (1.0f / (float)DCOLS);
        const float var = ss * (1.0f / (float)DCOLS) - mu * mu;
        const float rs  = rsqrtf(var + 1e-5f);
        f32x4 t0 = (px0 - mu) * rs * g0 + b0;
        f32x4 t1 = (px1 - mu) * rs * g1 + b1;
        *(f32x4*)(s_q + c0) = t0;
        *(f32x4*)(s_q + c1) = t1;
        __builtin_nontemporal_store(t0, (f32x4*)(ob + c0));
        __builtin_nontemporal_store(t1, (f32x4*)(ob + c1));
    }
    __syncthreads();   // barrier 1: q visible

    const f32x4 q0 = *(const f32x4*)(s_q + c0);
    const f32x4 q1 = *(const f32x4*)(s_q + c1);

    // ---- Fused pass 1+2: LN stats + score per owned row (e transient) ----
#pragma unroll
    for (int i = 0; i < RPW; ++i) {
        const int r = r0 + i;
        const f32x4 x0 = (i == 0) ? px0 : *(const f32x4*)(eb + r * DCOLS + c0);
        const f32x4 x1 = (i == 0) ? px1 : *(const f32x4*)(eb + r * DCOLS + c1);
        float s = hsum8(x0, x1), ss = hsumsq8(x0, x1);
        wave_reduce_sum2(s, ss);
        const float mu  = s * (1.0f / (float)DCOLS);
        const float var = ss * (1.0f / (float)DCOLS) - mu * mu;
        const float rs  = rsqrtf(var + 1e-5f);
        if (lane == 0) { s_nmu[r] = -mu * rs; s_rs[r] = rs; }

        const f32x4 e0v = (x0 - mu) * rs * g0 + b0;
        const f32x4 e1v = (x1 - mu) * rs * g1 + b1;
        float p;
        p  = fast_tanh(q0.x * e0v.x) * w0.x;
        p += fast_tanh(q0.y * e0v.y) * w0.y;
        p += fast_tanh(q0.z * e0v.z) * w0.z;
        p += fast_tanh(q0.w * e0v.w) * w0.w;
        p += fast_tanh(q1.x * e1v.x) * w1.x;
        p += fast_tanh(q1.y * e1v.y) * w1.y;
        p += fast_tanh(q1.z * e1v.z) * w1.z;
        p += fast_tanh(q1.w * e1v.w) * w1.w;

        const float tot = wave_reduce_sum(p) + bias;
        if (lane == 0) s_sc[r] = (r > 0) ? tot : -1e30f;
    }
    __syncthreads();   // barrier 2: scores + per-row LN stats visible

    // ---- Softmax stats: every wave reduces the 64-entry score vector ----
    const float v   = s_sc[lane];
    const float mx  = wave_reduce_max(v);
    const float den = wave_reduce_sum(__expf(v - mx));   // row-0 sentinel -> 0
    const float inv = 1.0f / den;

    // ---- Pass 3: re-read x (L2/L3-hot), recompute e, scale, store ----
#pragma unroll
    for (int i = 0; i < RPW; ++i) {
        const int r = r0 + i;
        if (r == 0) continue;   // only wave 0, i==0
        const float a  = __expf(s_sc[r] - mx) * inv;
        const float rs = s_rs[r];
        const float nm = s_nmu[r];
        const f32x4 x0 = *(const f32x4*)(eb + r * DCOLS + c0);
        const f32x4 x1 = *(const f32x4*)(eb + r * DCOLS + c1);
        const f32x4 o0 = ((x0 * rs + nm) * g0 + b0) * a;
        const f32x4 o1 = ((x1 * rs + nm) * g1 + b1) * a;
        __builtin_nontemporal_store(o0, (f32x4*)(ob + r * DCOLS + c0));
        __builtin_nontemporal_store(o1, (f32x4*)(ob + r * DCOLS + c1));
    }
}

extern "C" void kernel_launch(void* const* d_in, const int* in_sizes, int n_in,
                              void* d_out, int out_size, void* d_ws, size_t ws_size,
                              hipStream_t stream) {
    const float* emb   = (const float*)d_in[0];
    const float* gamma = (const float*)d_in[1];
    const float* beta  = (const float*)d_in[2];
    const float* Wv    = (const float*)d_in[3];
    const float* bv    = (const float*)d_in[4];
    float* out = (float*)d_out;

    const int B = in_sizes[0] / (NROWS * DCOLS);
    fused_ln_attn_kernel<<<B, BDIM, 0, stream>>>(emb, gamma, beta, Wv, bv, out);
}

// Round 7
// 266.053 us; speedup vs baseline: 1.2136x; 1.2136x over previous
//
#include <hip/hip_runtime.h>
#include <math.h>

#define NROWS 64
#define DCOLS 512
#define HCOL  256   // columns per half
#define BDIM  1024
#define RPW   4     // rows per wave: 64 rows / 16 waves

typedef float f32x4 __attribute__((ext_vector_type(4)));

__device__ __forceinline__ void wave_reduce_sum2(float& a, float& b) {
#pragma unroll
    for (int off = 32; off > 0; off >>= 1) {
        a += __shfl_xor(a, off, 64);
        b += __shfl_xor(b, off, 64);
    }
}
__device__ __forceinline__ float wave_reduce_sum(float v) {
#pragma unroll
    for (int off = 32; off > 0; off >>= 1)
        v += __shfl_xor(v, off, 64);
    return v;
}
__device__ __forceinline__ float wave_reduce_max(float v) {
#pragma unroll
    for (int off = 32; off > 0; off >>= 1)
        v = fmaxf(v, __shfl_xor(v, off, 64));
    return v;
}

__device__ __forceinline__ float hsum8(f32x4 a, f32x4 b) {
    return ((a.x + a.y) + (a.z + a.w)) + ((b.x + b.y) + (b.z + b.w));
}
__device__ __forceinline__ float hsumsq8(f32x4 a, f32x4 b) {
    return (a.x*a.x + a.y*a.y + a.z*a.z + a.w*a.w)
         + (b.x*b.x + b.y*b.y + b.z*b.z + b.w*b.w);
}

// tanh(x) = 1 - 2/(exp(2x)+1); correct both signs, saturates at +/-1.
__device__ __forceinline__ float fast_tanh(float x) {
    float e = __expf(2.0f * x);
    return 1.0f - 2.0f / (e + 1.0f);
}

__global__ __launch_bounds__(BDIM, 4) void fused_ln_attn_kernel(
    const float* __restrict__ emb,
    const float* __restrict__ gamma,
    const float* __restrict__ beta,
    const float* __restrict__ Wv,
    const float* __restrict__ bv,
    float* __restrict__ out)
{
    __shared__ float s_q[DCOLS];
    __shared__ float s_sc[NROWS];          // scores; s_sc[0] = -inf sentinel
    __shared__ float s_e1[NROWS * HCOL];   // 64 KiB: c1-half of e, thread-private slots

    const int tid  = threadIdx.x;
    const int wave = tid >> 6;
    const int lane = tid & 63;
    const int c0   = lane << 2;          // columns [c0, c0+4)
    const int c1   = HCOL + c0;          // columns [c1, c1+4)

    const size_t base = (size_t)blockIdx.x * (size_t)(NROWS * DCOLS);
    const float* eb = emb + base;
    float*       ob = out + base;

    float4_pad_guard: ;   // (no-op label to keep structure obvious)

    f32x4 e0[RPW];   // c0-half stays in registers; c1-half lives in LDS

    // ---- Pass 1: LayerNorm each owned row (gamma/beta live only here) ----
    {
        const f32x4 g0 = *(const f32x4*)(gamma + c0);
        const f32x4 g1 = *(const f32x4*)(gamma + c1);
        const f32x4 b0 = *(const f32x4*)(beta + c0);
        const f32x4 b1 = *(const f32x4*)(beta + c1);

#pragma unroll
        for (int i = 0; i < RPW; ++i) {
            const int r = wave * RPW + i;
            const float* rp = eb + r * DCOLS;
            const f32x4 x0 = *(const f32x4*)(rp + c0);
            const f32x4 x1 = *(const f32x4*)(rp + c1);

            float s = hsum8(x0, x1), ss = hsumsq8(x0, x1);
            wave_reduce_sum2(s, ss);

            const float mu  = s * (1.0f / (float)DCOLS);
            const float var = ss * (1.0f / (float)DCOLS) - mu * mu;
            const float rs  = rsqrtf(var + 1e-5f);

            const f32x4 t0 = (x0 - mu) * rs * g0 + b0;
            const f32x4 t1 = (x1 - mu) * rs * g1 + b1;

            e0[i] = t0;
            *(f32x4*)(s_e1 + r * HCOL + c0) = t1;   // own slot; same thread reads it back

            if (wave == 0 && i == 0) {
                // query row: publish to all waves + write straight to output
                *(f32x4*)(s_q + c0) = t0;
                *(f32x4*)(s_q + c1) = t1;
                __builtin_nontemporal_store(t0, (f32x4*)(ob + c0));
                __builtin_nontemporal_store(t1, (f32x4*)(ob + c1));
            }
        }
    }
    __syncthreads();   // barrier 1: q + e1 halves visible

    // loaded after barrier so they are not live through pass 1
    const f32x4 q0  = *(const f32x4*)(s_q + c0);
    const f32x4 q1  = *(const f32x4*)(s_q + c1);
    const f32x4 w0  = *(const f32x4*)(Wv + c0);
    const f32x4 w1  = *(const f32x4*)(Wv + c1);
    const float bias = bv[0];

    // ---- Pass 2: scores_r = sum_d tanh(q_d * e_rd) * Wv_d + bv ----
    float sc[RPW];
#pragma unroll
    for (int i = 0; i < RPW; ++i) {
        const int r = wave * RPW + i;
        const f32x4 t1 = *(const f32x4*)(s_e1 + r * HCOL + c0);
        float p = 0.0f;
        if (r > 0) {
            p  = fast_tanh(q0.x * e0[i].x) * w0.x;
            p += fast_tanh(q0.y * e0[i].y) * w0.y;
            p += fast_tanh(q0.z * e0[i].z) * w0.z;
            p += fast_tanh(q0.w * e0[i].w) * w0.w;
            p += fast_tanh(q1.x * t1.x) * w1.x;
            p += fast_tanh(q1.y * t1.y) * w1.y;
            p += fast_tanh(q1.z * t1.z) * w1.z;
            p += fast_tanh(q1.w * t1.w) * w1.w;
        }
        const float tot = wave_reduce_sum(p) + bias;
        sc[i] = tot;
        if (lane == 0) s_sc[r] = (r > 0) ? tot : -1e30f;
    }
    __syncthreads();   // barrier 2: all scores visible

    // ---- Softmax stats: every wave reduces the 64-entry score vector ----
    const float v   = s_sc[lane];
    const float mx  = wave_reduce_max(v);
    const float den = wave_reduce_sum(__expf(v - mx));   // row-0 sentinel -> 0
    const float inv = 1.0f / den;

    // ---- Pass 3: out_r = alpha_r * e_r for key rows ----
#pragma unroll
    for (int i = 0; i < RPW; ++i) {
        const int r = wave * RPW + i;
        if (r == 0) continue;   // row 0 already written (it's q)
        const float a  = __expf(sc[i] - mx) * inv;
        const f32x4 t1 = *(const f32x4*)(s_e1 + r * HCOL + c0);
        const f32x4 o0 = e0[i] * a;
        const f32x4 o1 = t1 * a;
        __builtin_nontemporal_store(o0, (f32x4*)(ob + r * DCOLS + c0));
        __builtin_nontemporal_store(o1, (f32x4*)(ob + r * DCOLS + c1));
    }
}

extern "C" void kernel_launch(void* const* d_in, const int* in_sizes, int n_in,
                              void* d_out, int out_size, void* d_ws, size_t ws_size,
                              hipStream_t stream) {
    const float* emb   = (const float*)d_in[0];
    const float* gamma = (const float*)d_in[1];
    const float* beta  = (const float*)d_in[2];
    const float* Wv    = (const float*)d_in[3];
    const float* bv    = (const float*)d_in[4];
    float* out = (float*)d_out;

    const int B = in_sizes[0] / (NROWS * DCOLS);
    fused_ln_attn_kernel<<<B, BDIM, 0, stream>>>(emb, gamma, beta, Wv, bv, out);
}